// Round 17
// baseline (300.657 us; speedup 1.0000x reference)
//
#include <hip/hip_runtime.h>
#include <hip/hip_bf16.h>

// Problem constants
#define BATCH   4096
#define NF      128    // n features == n models
#define NA      16
#define IN_DIM  144    // K = 144 exactly (9 MFMA k-steps of 16; 18 8-elem chunks)
#define KP      144    // w1t K (b1 folded via MFMA C-operand)
#define HID     256

typedef __attribute__((ext_vector_type(8))) short bf16x8;
typedef __attribute__((ext_vector_type(4))) float f32x4;
typedef __attribute__((ext_vector_type(16))) float f32x16;

// ---------------------------------------------------------------------------
// Merged convert kernel:
//   blocks [0, 1152):      W1 [128][144][256] fp32 -> w1t [128][256][144] bf16
//                          (transposed; b1 folded later via MFMA C-operand)
//   blocks [1152, 1440):   fa -> fab2 bf16, K-CHUNK-MAJOR [18][4096][8]:
//                          plane kc holds k = kc*8..kc*8+8 for all rows ->
//                          a half-wave's frag load is 512 B contiguous.
__global__ void convert_all(const float* __restrict__ W1,
                            const float* __restrict__ f_t,
                            const float* __restrict__ a_t,
                            __hip_bfloat16* __restrict__ w1t,
                            __hip_bfloat16* __restrict__ fab2) {
    const int bid = blockIdx.x;
    const int t = threadIdx.x;
    if (bid < 1152) {
        __shared__ float tile[16][HID];
        int m = bid / 9;
        int kc = bid - m * 9;
        int k0 = kc * 16;
#pragma unroll
        for (int i = 0; i < 16; ++i)
            tile[i][t] = W1[((size_t)m * IN_DIM + (k0 + i)) * HID + t];
        __syncthreads();
        union { ushort us[16]; uint4 q[2]; } pk;
#pragma unroll
        for (int i = 0; i < 16; ++i) {
            __hip_bfloat16 h = __float2bfloat16(tile[i][t]);
            pk.us[i] = *(ushort*)&h;
        }
        uint4* dst = (uint4*)(w1t + ((size_t)m * HID + t) * KP + k0);
        dst[0] = pk.q[0];
        dst[1] = pk.q[1];
    } else {
        int b2i = bid - 1152;          // 0..287
        int cc = b2i / 16;             // k-chunk 0..17
        int rb = b2i - cc * 16;        // row block 0..15
        int row = rb * 256 + t;
        union { ushort us[8]; uint4 q; } pk;
        const float* src = (cc < 16) ? (f_t + (size_t)row * NF + cc * 8)
                                     : (a_t + (size_t)row * NA + (cc - 16) * 8);
#pragma unroll
        for (int j = 0; j < 8; ++j) {
            __hip_bfloat16 h = __float2bfloat16(src[j]);
            pk.us[j] = *(ushort*)&h;
        }
        *(uint4*)(fab2 + ((size_t)cc * BATCH + row) * 8) = pk.q;   // coalesced
    }
}

// ---------------------------------------------------------------------------
// Fused grouped MLP — barrier-free loop, 2-deep register prefetch, 4 blocks/CU.
// Grid 1024 = 128 m (bid&127) x 8 slices of 512 rows; 16 tiles of 32 rows.
// 256 thr = 4 waves; wave w owns hid cols [w*64, w*64+64) = 2 x 32-tiles.
// VGPR<=128 + LDS 8 KB -> 4 blocks/CU = 4 waves/SIMD: enough independent
// streams for the scheduler to de-phase MFMA/VALU/vmem across waves (the
// R15 limiter was 2 phase-aligned waves/SIMD).
// mfma(A=w1t frag, B=fa frag): D[row=hid][col=batch].
//  A/B frag (32x32x16): lane holds row/col (lane&31), k = (lane>>5)*8 + j.
//  C/D: col = lane&31, row = (reg&3) + 8*(reg>>2) + 4*(lane>>5).
__global__ __launch_bounds__(256, 4) void fused_mlp(
        const __hip_bfloat16* __restrict__ fab2,
        const __hip_bfloat16* __restrict__ w1t,
        const float* __restrict__ b1,
        const float* __restrict__ W2,
        const float* __restrict__ b2,
        const float* __restrict__ f_t,
        float* __restrict__ out) {
    __shared__ __align__(16) float partial[16][4][32];   // 8 KB

    const int bid = blockIdx.x;
    const int m     = bid & 127;     // same-m blocks 128 apart -> same XCD L2
    const int slice = bid >> 7;      // 0..7, 512 rows each
    const int row_base = slice * 512;
    const int t = threadIdx.x;
    const int w = t >> 6;            // wave = hid col group 0..3 (64 cols)
    const int lane = t & 63;
    const int l31 = lane & 31;
    const int h = lane >> 5;         // 0..1 (k-half / hid-row-half selector)

    // ---- prologue: W1T frags (MFMA A operand): hid = l31 (+32*hi2),
    // k = ks*16 + h*8 .. +8  -> b128 loads from w1t.
    bf16x8 bfrag[2][9];
#pragma unroll
    for (int hi2 = 0; hi2 < 2; ++hi2) {
        const int col = w * 64 + hi2 * 32 + l31;
        const __hip_bfloat16* wp = w1t + ((size_t)m * HID + col) * KP + h * 8;
#pragma unroll
        for (int ks = 0; ks < 9; ++ks)
            bfrag[hi2][ks] = *(const bf16x8*)(wp + ks * 16);
    }
    // w2v/b1v [hi2][reg]: reg = q*4+i -> hid row 8q + 4h + i
    f32x16 w2v[2], b1v[2];
#pragma unroll
    for (int hi2 = 0; hi2 < 2; ++hi2) {
        const float* wp2 = W2 + (size_t)m * HID + w * 64 + hi2 * 32 + 4 * h;
        const float* bp1 = b1 + (size_t)m * HID + w * 64 + hi2 * 32 + 4 * h;
#pragma unroll
        for (int q = 0; q < 4; ++q) {
            f32x4 v = *(const f32x4*)(wp2 + 8 * q);
            f32x4 bv = *(const f32x4*)(bp1 + 8 * q);
#pragma unroll
            for (int i = 0; i < 4; ++i) {
                w2v[hi2][q * 4 + i] = v[i];
                b1v[hi2][q * 4 + i] = bv[i];
            }
        }
    }
    const float b2v = b2[m];

    // per-lane A base: plane h, row column l31
    const __hip_bfloat16* fbase = fab2 + ((size_t)h * BATCH + l31) * 8;

    // load tile at row RR into BUF (compile-time ks indices -> registers)
#define LOADT(BUF, RR)                                                        \
    {                                                                         \
        const __hip_bfloat16* fb = fbase + (size_t)(RR) * 8;                  \
        _Pragma("unroll")                                                     \
        for (int ks = 0; ks < 9; ++ks)                                        \
            BUF[ks] = *(const bf16x8*)(fb + (size_t)ks * 2 * BATCH * 8);      \
    }

    // compute one 32-row tile TL from BUF, write partial (no sync)
#define COMPT(BUF, TL)                                                        \
    {                                                                         \
        f32x16 acc[2];                                                        \
        _Pragma("unroll")                                                     \
        for (int hi2 = 0; hi2 < 2; ++hi2)                                     \
            acc[hi2] = __builtin_amdgcn_mfma_f32_32x32x16_bf16(               \
                bfrag[hi2][0], BUF[0], b1v[hi2], 0, 0, 0);                    \
        _Pragma("unroll")                                                     \
        for (int ks = 1; ks < 9; ++ks)                                        \
            _Pragma("unroll")                                                 \
            for (int hi2 = 0; hi2 < 2; ++hi2)                                 \
                acc[hi2] = __builtin_amdgcn_mfma_f32_32x32x16_bf16(           \
                    bfrag[hi2][ks], BUF[ks], acc[hi2], 0, 0, 0);              \
        float sr0 = 0.f, sr1 = 0.f, sr2 = 0.f, sr3 = 0.f;                     \
        _Pragma("unroll")                                                     \
        for (int hi2 = 0; hi2 < 2; ++hi2)                                     \
            _Pragma("unroll")                                                 \
            for (int q = 0; q < 4; ++q) {                                     \
                float h0 = acc[hi2][q*4+0]; h0 = h0 > 0.f ? h0 : 0.f;         \
                float h1 = acc[hi2][q*4+1]; h1 = h1 > 0.f ? h1 : 0.f;         \
                float h2 = acc[hi2][q*4+2]; h2 = h2 > 0.f ? h2 : 0.f;         \
                float h3 = acc[hi2][q*4+3]; h3 = h3 > 0.f ? h3 : 0.f;         \
                sr0 = fmaf(h0, w2v[hi2][q*4+0], sr0);                         \
                sr1 = fmaf(h1, w2v[hi2][q*4+1], sr1);                         \
                sr2 = fmaf(h2, w2v[hi2][q*4+2], sr2);                         \
                sr3 = fmaf(h3, w2v[hi2][q*4+3], sr3);                         \
            }                                                                 \
        float s = (sr0 + sr1) + (sr2 + sr3);                                  \
        s += __shfl_xor(s, 32, 64);                                           \
        if (h == 0) partial[TL][w][l31] = s;                                  \
    }

    bf16x8 bufA[9], bufB[9];
    LOADT(bufA, row_base);
#pragma unroll 4
    for (int tp = 0; tp < 8; ++tp) {
        const int t0 = 2 * tp;
        LOADT(bufB, row_base + (t0 + 1) * 32);       // prefetch odd tile
        COMPT(bufA, t0);
        if (t0 + 2 < 16) LOADT(bufA, row_base + (t0 + 2) * 32);  // prefetch next even
        COMPT(bufB, t0 + 1);
    }
#undef LOADT
#undef COMPT

    // ---- single barrier, then combine all 16 tiles (512 outputs/block)
    __syncthreads();
#pragma unroll
    for (int i = 0; i < 2; ++i) {
        int idx = i * 256 + t;             // 0..511
        int tl = idx >> 5;
        int r  = idx & 31;
        int row = row_base + tl * 32 + r;
        float v = (partial[tl][0][r] + partial[tl][1][r])
                + (partial[tl][2][r] + partial[tl][3][r])
                + b2v + f_t[(size_t)row * NF + m];
        out[(size_t)row * NF + m] = v;
    }
}

// ---------------------------------------------------------------------------
extern "C" void kernel_launch(void* const* d_in, const int* in_sizes, int n_in,
                              void* d_out, int out_size, void* d_ws, size_t ws_size,
                              hipStream_t stream) {
    const float* f_t = (const float*)d_in[0];
    const float* a_t = (const float*)d_in[1];
    const float* W1  = (const float*)d_in[2];
    const float* b1  = (const float*)d_in[3];
    const float* W2  = (const float*)d_in[4];
    const float* b2  = (const float*)d_in[5];
    float* out = (float*)d_out;

    // ws layout: w1t bf16 [128][256][144] (9.44 MB),
    //            fab2 bf16 [18][4096][8] k-chunk-major (1.18 MB)
    __hip_bfloat16* w1t  = (__hip_bfloat16*)d_ws;
    __hip_bfloat16* fab2 = (__hip_bfloat16*)((char*)d_ws + (size_t)NF * HID * KP * 2);

    // converts merged: 1152 w1t blocks + 288 fab2 blocks
    hipLaunchKernelGGL(convert_all, dim3(1440), dim3(256), 0, stream,
                       W1, f_t, a_t, w1t, fab2);
    hipLaunchKernelGGL(fused_mlp, dim3(1024), dim3(256), 0, stream,
                       fab2, w1t, b1, W2, b2, f_t, out);
}

// Round 18
// 57.928 us; speedup vs baseline: 5.1902x; 5.1902x over previous
//
#include <hip/hip_runtime.h>
#include <hip/hip_bf16.h>

// Problem constants
#define BATCH   4096
#define NF      128    // n features == n models
#define NA      16
#define IN_DIM  144    // K = 144 exactly (9 MFMA k-steps of 16; 18 8-elem chunks)
#define KP      144    // w1t K (b1 folded via MFMA C-operand)
#define HID     256

typedef __attribute__((ext_vector_type(8))) short bf16x8;
typedef __attribute__((ext_vector_type(4))) float f32x4;
typedef __attribute__((ext_vector_type(16))) float f32x16;

// ---------------------------------------------------------------------------
// Merged convert kernel:
//   blocks [0, 1152):      W1 [128][144][256] fp32 -> w1t [128][256][144] bf16
//                          (transposed; b1 folded later via MFMA C-operand)
//   blocks [1152, 1440):   fa -> fab2 bf16, K-CHUNK-MAJOR [18][4096][8]:
//                          plane kc holds k = kc*8..kc*8+8 for all rows ->
//                          a half-wave's frag load is 512 B contiguous.
__global__ void convert_all(const float* __restrict__ W1,
                            const float* __restrict__ f_t,
                            const float* __restrict__ a_t,
                            __hip_bfloat16* __restrict__ w1t,
                            __hip_bfloat16* __restrict__ fab2) {
    const int bid = blockIdx.x;
    const int t = threadIdx.x;
    if (bid < 1152) {
        __shared__ float tile[16][HID];
        int m = bid / 9;
        int kc = bid - m * 9;
        int k0 = kc * 16;
#pragma unroll
        for (int i = 0; i < 16; ++i)
            tile[i][t] = W1[((size_t)m * IN_DIM + (k0 + i)) * HID + t];
        __syncthreads();
        union { ushort us[16]; uint4 q[2]; } pk;
#pragma unroll
        for (int i = 0; i < 16; ++i) {
            __hip_bfloat16 h = __float2bfloat16(tile[i][t]);
            pk.us[i] = *(ushort*)&h;
        }
        uint4* dst = (uint4*)(w1t + ((size_t)m * HID + t) * KP + k0);
        dst[0] = pk.q[0];
        dst[1] = pk.q[1];
    } else {
        int b2i = bid - 1152;          // 0..287
        int cc = b2i / 16;             // k-chunk 0..17
        int rb = b2i - cc * 16;        // row block 0..15
        int row = rb * 256 + t;
        union { ushort us[8]; uint4 q; } pk;
        const float* src = (cc < 16) ? (f_t + (size_t)row * NF + cc * 8)
                                     : (a_t + (size_t)row * NA + (cc - 16) * 8);
#pragma unroll
        for (int j = 0; j < 8; ++j) {
            __hip_bfloat16 h = __float2bfloat16(src[j]);
            pk.us[j] = *(ushort*)&h;
        }
        *(uint4*)(fab2 + ((size_t)cc * BATCH + row) * 8) = pk.q;   // coalesced
    }
}

// ---------------------------------------------------------------------------
// Fused grouped MLP — barrier-free loop, 2-deep register prefetch.
// Grid 1024 = 128 m (bid&127) x 8 slices of 512 rows; 16 tiles of 32 rows.
// 256 thr = 4 waves; wave w owns hid cols [w*64, w*64+64) = 2 x 32-tiles.
// launch_bounds(256,2): loose cap (256 VGPR) -> compiler's natural 128-VGPR
// allocation (R15-proven, no scratch). With VGPR=128 + LDS 8 KB the HW can
// then resident 4 blocks/CU = 4 de-phased wave-streams per SIMD (R17's
// (256,4) hard cap forced a catastrophic spill: VGPR 64, 920 MB scratch).
// mfma(A=w1t frag, B=fa frag): D[row=hid][col=batch].
//  A/B frag (32x32x16): lane holds row/col (lane&31), k = (lane>>5)*8 + j.
//  C/D: col = lane&31, row = (reg&3) + 8*(reg>>2) + 4*(lane>>5).
__global__ __launch_bounds__(256, 2) void fused_mlp(
        const __hip_bfloat16* __restrict__ fab2,
        const __hip_bfloat16* __restrict__ w1t,
        const float* __restrict__ b1,
        const float* __restrict__ W2,
        const float* __restrict__ b2,
        const float* __restrict__ f_t,
        float* __restrict__ out) {
    __shared__ __align__(16) float partial[16][4][32];   // 8 KB

    const int bid = blockIdx.x;
    const int m     = bid & 127;     // same-m blocks 128 apart -> same XCD L2
    const int slice = bid >> 7;      // 0..7, 512 rows each
    const int row_base = slice * 512;
    const int t = threadIdx.x;
    const int w = t >> 6;            // wave = hid col group 0..3 (64 cols)
    const int lane = t & 63;
    const int l31 = lane & 31;
    const int h = lane >> 5;         // 0..1 (k-half / hid-row-half selector)

    // ---- prologue: W1T frags (MFMA A operand): hid = l31 (+32*hi2),
    // k = ks*16 + h*8 .. +8  -> b128 loads from w1t.
    bf16x8 bfrag[2][9];
#pragma unroll
    for (int hi2 = 0; hi2 < 2; ++hi2) {
        const int col = w * 64 + hi2 * 32 + l31;
        const __hip_bfloat16* wp = w1t + ((size_t)m * HID + col) * KP + h * 8;
#pragma unroll
        for (int ks = 0; ks < 9; ++ks)
            bfrag[hi2][ks] = *(const bf16x8*)(wp + ks * 16);
    }
    // w2v/b1v [hi2][reg]: reg = q*4+i -> hid row 8q + 4h + i
    f32x16 w2v[2], b1v[2];
#pragma unroll
    for (int hi2 = 0; hi2 < 2; ++hi2) {
        const float* wp2 = W2 + (size_t)m * HID + w * 64 + hi2 * 32 + 4 * h;
        const float* bp1 = b1 + (size_t)m * HID + w * 64 + hi2 * 32 + 4 * h;
#pragma unroll
        for (int q = 0; q < 4; ++q) {
            f32x4 v = *(const f32x4*)(wp2 + 8 * q);
            f32x4 bv = *(const f32x4*)(bp1 + 8 * q);
#pragma unroll
            for (int i = 0; i < 4; ++i) {
                w2v[hi2][q * 4 + i] = v[i];
                b1v[hi2][q * 4 + i] = bv[i];
            }
        }
    }
    const float b2v = b2[m];

    // per-lane A base: plane h, row column l31
    const __hip_bfloat16* fbase = fab2 + ((size_t)h * BATCH + l31) * 8;

    // load tile at row RR into BUF (compile-time ks indices -> registers)
#define LOADT(BUF, RR)                                                        \
    {                                                                         \
        const __hip_bfloat16* fb = fbase + (size_t)(RR) * 8;                  \
        _Pragma("unroll")                                                     \
        for (int ks = 0; ks < 9; ++ks)                                        \
            BUF[ks] = *(const bf16x8*)(fb + (size_t)ks * 2 * BATCH * 8);      \
    }

    // compute one 32-row tile TL from BUF, write partial (no sync)
#define COMPT(BUF, TL)                                                        \
    {                                                                         \
        f32x16 acc[2];                                                        \
        _Pragma("unroll")                                                     \
        for (int hi2 = 0; hi2 < 2; ++hi2)                                     \
            acc[hi2] = __builtin_amdgcn_mfma_f32_32x32x16_bf16(               \
                bfrag[hi2][0], BUF[0], b1v[hi2], 0, 0, 0);                    \
        _Pragma("unroll")                                                     \
        for (int ks = 1; ks < 9; ++ks)                                        \
            _Pragma("unroll")                                                 \
            for (int hi2 = 0; hi2 < 2; ++hi2)                                 \
                acc[hi2] = __builtin_amdgcn_mfma_f32_32x32x16_bf16(           \
                    bfrag[hi2][ks], BUF[ks], acc[hi2], 0, 0, 0);              \
        float sr0 = 0.f, sr1 = 0.f, sr2 = 0.f, sr3 = 0.f;                     \
        _Pragma("unroll")                                                     \
        for (int hi2 = 0; hi2 < 2; ++hi2)                                     \
            _Pragma("unroll")                                                 \
            for (int q = 0; q < 4; ++q) {                                     \
                float h0 = acc[hi2][q*4+0]; h0 = h0 > 0.f ? h0 : 0.f;         \
                float h1 = acc[hi2][q*4+1]; h1 = h1 > 0.f ? h1 : 0.f;         \
                float h2 = acc[hi2][q*4+2]; h2 = h2 > 0.f ? h2 : 0.f;         \
                float h3 = acc[hi2][q*4+3]; h3 = h3 > 0.f ? h3 : 0.f;         \
                sr0 = fmaf(h0, w2v[hi2][q*4+0], sr0);                         \
                sr1 = fmaf(h1, w2v[hi2][q*4+1], sr1);                         \
                sr2 = fmaf(h2, w2v[hi2][q*4+2], sr2);                         \
                sr3 = fmaf(h3, w2v[hi2][q*4+3], sr3);                         \
            }                                                                 \
        float s = (sr0 + sr1) + (sr2 + sr3);                                  \
        s += __shfl_xor(s, 32, 64);                                           \
        if (h == 0) partial[TL][w][l31] = s;                                  \
    }

    bf16x8 bufA[9], bufB[9];
    LOADT(bufA, row_base);
#pragma unroll 4
    for (int tp = 0; tp < 8; ++tp) {
        const int t0 = 2 * tp;
        LOADT(bufB, row_base + (t0 + 1) * 32);       // prefetch odd tile
        COMPT(bufA, t0);
        if (t0 + 2 < 16) LOADT(bufA, row_base + (t0 + 2) * 32);  // prefetch next even
        COMPT(bufB, t0 + 1);
    }
#undef LOADT
#undef COMPT

    // ---- single barrier, then combine all 16 tiles (512 outputs/block)
    __syncthreads();
#pragma unroll
    for (int i = 0; i < 2; ++i) {
        int idx = i * 256 + t;             // 0..511
        int tl = idx >> 5;
        int r  = idx & 31;
        int row = row_base + tl * 32 + r;
        float v = (partial[tl][0][r] + partial[tl][1][r])
                + (partial[tl][2][r] + partial[tl][3][r])
                + b2v + f_t[(size_t)row * NF + m];
        out[(size_t)row * NF + m] = v;
    }
}

// ---------------------------------------------------------------------------
extern "C" void kernel_launch(void* const* d_in, const int* in_sizes, int n_in,
                              void* d_out, int out_size, void* d_ws, size_t ws_size,
                              hipStream_t stream) {
    const float* f_t = (const float*)d_in[0];
    const float* a_t = (const float*)d_in[1];
    const float* W1  = (const float*)d_in[2];
    const float* b1  = (const float*)d_in[3];
    const float* W2  = (const float*)d_in[4];
    const float* b2  = (const float*)d_in[5];
    float* out = (float*)d_out;

    // ws layout: w1t bf16 [128][256][144] (9.44 MB),
    //            fab2 bf16 [18][4096][8] k-chunk-major (1.18 MB)
    __hip_bfloat16* w1t  = (__hip_bfloat16*)d_ws;
    __hip_bfloat16* fab2 = (__hip_bfloat16*)((char*)d_ws + (size_t)NF * HID * KP * 2);

    // converts merged: 1152 w1t blocks + 288 fab2 blocks
    hipLaunchKernelGGL(convert_all, dim3(1440), dim3(256), 0, stream,
                       W1, f_t, a_t, w1t, fab2);
    hipLaunchKernelGGL(fused_mlp, dim3(1024), dim3(256), 0, stream,
                       fab2, w1t, b1, W2, b2, f_t, out);
}

// Round 19
// 55.024 us; speedup vs baseline: 5.4641x; 1.0528x over previous
//
#include <hip/hip_runtime.h>
#include <hip/hip_bf16.h>

// Problem constants
#define BATCH   4096
#define NF      128    // n features == n models
#define NA      16
#define IN_DIM  144    // K = 144 exactly (9 MFMA k-steps of 16; 18 8-elem chunks)
#define KP      144    // w1t K (b1 folded via MFMA C-operand)
#define NCH     18     // 16B chunks per row (144 bf16 / 8)
#define HID     256

typedef __attribute__((ext_vector_type(8))) short bf16x8;
typedef __attribute__((ext_vector_type(4))) float f32x4;
typedef __attribute__((ext_vector_type(16))) float f32x16;
typedef unsigned int u32;

// async global->LDS, 16B per lane. LDS dest must be wave-uniform base + lane*16.
__device__ __forceinline__ void gl_lds16(const void* gsrc, void* ldst) {
    __builtin_amdgcn_global_load_lds(
        (const __attribute__((address_space(1))) u32*)gsrc,
        (__attribute__((address_space(3))) u32*)ldst, 16, 0, 0);
}

// ---------------------------------------------------------------------------
// Merged convert kernel:
//   blocks [0, 1152):      W1 [128][144][256] fp32 -> w1t [128][256][144] bf16
//                          (transposed; b1 folded via MFMA C-operand later)
//   blocks [1152, 1440):   fa -> fabT bf16, CHUNK-MAJOR PER 64-ROW TILE:
//                          fabT[tile][chunk 0..17][row 0..63] (16B units).
//                          A 32-lane frag read = 512 B contiguous -> zero
//                          LDS bank conflicts without any swizzle.
__global__ void convert_all(const float* __restrict__ W1,
                            const float* __restrict__ f_t,
                            const float* __restrict__ a_t,
                            __hip_bfloat16* __restrict__ w1t,
                            __hip_bfloat16* __restrict__ fabT) {
    const int bid = blockIdx.x;
    const int t = threadIdx.x;
    if (bid < 1152) {
        __shared__ float tile[16][HID];
        int m = bid / 9;
        int kc = bid - m * 9;
        int k0 = kc * 16;
#pragma unroll
        for (int i = 0; i < 16; ++i)
            tile[i][t] = W1[((size_t)m * IN_DIM + (k0 + i)) * HID + t];
        __syncthreads();
        union { ushort us[16]; uint4 q[2]; } pk;
#pragma unroll
        for (int i = 0; i < 16; ++i) {
            __hip_bfloat16 h = __float2bfloat16(tile[i][t]);
            pk.us[i] = *(ushort*)&h;
        }
        uint4* dst = (uint4*)(w1t + ((size_t)m * HID + t) * KP + k0);
        dst[0] = pk.q[0];
        dst[1] = pk.q[1];
    } else {
        // output chunk index o = ((T*18 + cc)*64 + r); writes coalesced in t.
        int o = (bid - 1152) * 256 + t;
        const int total = (BATCH / 64) * NCH * 64;   // 73728
        if (o >= total) return;
        int r  = o & 63;
        int cc = (o >> 6) % NCH;
        int T  = o / (NCH * 64);
        int row = T * 64 + r;
        union { ushort us[8]; uint4 q; } pk;
        const float* src = (cc < 16) ? (f_t + (size_t)row * NF + cc * 8)
                                     : (a_t + (size_t)row * NA + (cc - 16) * 8);
#pragma unroll
        for (int j = 0; j < 8; ++j) {
            __hip_bfloat16 h = __float2bfloat16(src[j]);
            pk.us[j] = *(ushort*)&h;
        }
        *(uint4*)(fabT + (size_t)o * 8) = pk.q;
    }
}

// ---------------------------------------------------------------------------
// Fused grouped MLP — R13 schedule (gl_lds dbuf, 1 barrier/tile) with the
// conflict-free chunk-major LDS layout (no swizzle needed).
// Grid 1024 = 128 m (bid&127) x 8 slices of 512 rows; 8 tiles of 64 rows.
// 256 thr = 4 waves; wave w owns hid cols [w*64, w*64+64) = 2 x 32-tiles.
// B (W1T[m]) in registers; b1 folded via MFMA C-operand; K = 144.
// mfma(A=w1t frag, B=fa frag): D[row=hid][col=batch].
//  A/B frag (32x32x16): lane holds row/col (lane&31), k = (lane>>5)*8 + j.
//  C/D: col = lane&31, row = (reg&3) + 8*(reg>>2) + 4*(lane>>5).
__global__ __launch_bounds__(256, 2) void fused_mlp(
        const __hip_bfloat16* __restrict__ fabT,
        const __hip_bfloat16* __restrict__ w1t,
        const float* __restrict__ b1,
        const float* __restrict__ W2,
        const float* __restrict__ b2,
        const float* __restrict__ f_t,
        float* __restrict__ out) {
    __shared__ __align__(16) __hip_bfloat16 Abuf[2][NCH * 64 * 8];  // 2 x 18 KB
    __shared__ __align__(16) float partial[2][4][64];               // 2 KB

    const int bid = blockIdx.x;
    const int m     = bid & 127;     // same-m blocks 128 apart -> same XCD L2
    const int slice = bid >> 7;      // 0..7, 512 rows each
    const int row_base = slice * 512;
    const int T0 = row_base / 64;    // first 64-row tile index
    const int t = threadIdx.x;
    const int w = t >> 6;            // wave = hid col group 0..3 (64 cols)
    const int lane = t & 63;
    const int l31 = lane & 31;
    const int h = lane >> 5;         // 0..1 (k-half / hid-row-half selector)

    // ---- prologue: W1T frags (MFMA A operand): hid = l31 (+32*hi2),
    // k = ks*16 + h*8 .. +8  -> b128 loads from w1t.
    bf16x8 bfrag[2][9];
#pragma unroll
    for (int hi2 = 0; hi2 < 2; ++hi2) {
        const int col = w * 64 + hi2 * 32 + l31;
        const __hip_bfloat16* wp = w1t + ((size_t)m * HID + col) * KP + h * 8;
#pragma unroll
        for (int ks = 0; ks < 9; ++ks)
            bfrag[hi2][ks] = *(const bf16x8*)(wp + ks * 16);
    }
    // w2v/b1v [hi2][reg]: reg = q*4+i -> hid row 8q + 4h + i
    f32x16 w2v[2], b1v[2];
#pragma unroll
    for (int hi2 = 0; hi2 < 2; ++hi2) {
        const float* wp2 = W2 + (size_t)m * HID + w * 64 + hi2 * 32 + 4 * h;
        const float* bp1 = b1 + (size_t)m * HID + w * 64 + hi2 * 32 + 4 * h;
#pragma unroll
        for (int q = 0; q < 4; ++q) {
            f32x4 v = *(const f32x4*)(wp2 + 8 * q);
            f32x4 bv = *(const f32x4*)(bp1 + 8 * q);
#pragma unroll
            for (int i = 0; i < 4; ++i) {
                w2v[hi2][q * 4 + i] = v[i];
                b1v[hi2][q * 4 + i] = bv[i];
            }
        }
    }
    const float b2v = b2[m];

    // stage one 18 KB tile (1152 x 16B chunks): 4 full rounds + waves 0-1
#define STAGE(BUF, TG)                                                        \
    {                                                                         \
        const char* src = (const char*)fabT + (size_t)(TG) * (NCH * 64 * 16); \
        char* dst = (char*)&Abuf[BUF][0];                                     \
        _Pragma("unroll")                                                     \
        for (int i = 0; i < 4; ++i)                                           \
            gl_lds16(src + (size_t)(t + i * 256) * 16,                        \
                     dst + (t + i * 256) * 16);                               \
        if (t < 128)                                                          \
            gl_lds16(src + (size_t)(1024 + t) * 16, dst + (1024 + t) * 16);   \
    }

    STAGE(0, T0);
    __syncthreads();

    for (int tile = 0; tile < 8; ++tile) {
        const int cur = tile & 1;
        const int r0 = row_base + tile * 64;

        // issue next tile's stage early (drained by this tile's barrier)
        if (tile < 7) STAGE(cur ^ 1, T0 + tile + 1);

        // hoisted skip-connection gather (latency hidden under K-loop)
        float skipv = 0.0f;
        if (t < 64) skipv = f_t[(size_t)(r0 + t) * NF + m];

        f32x16 acc[2][2];   // [hi2][bj2]
        const char* ab = (const char*)&Abuf[cur][0];

        // ks = 0: C = b1 fragment (bias folded; no acc zero-init VALU)
        {
            bf16x8 a[2];   // chunk h, rows bj2*32 + l31 -> 512B contiguous
            a[0] = *(const bf16x8*)(ab + (h * 64 + l31) * 16);
            a[1] = *(const bf16x8*)(ab + (h * 64 + 32 + l31) * 16);
#pragma unroll
            for (int hi2 = 0; hi2 < 2; ++hi2)
#pragma unroll
                for (int bj2 = 0; bj2 < 2; ++bj2)
                    acc[hi2][bj2] = __builtin_amdgcn_mfma_f32_32x32x16_bf16(
                        bfrag[hi2][0], a[bj2], b1v[hi2], 0, 0, 0);
        }
#pragma unroll
        for (int ks = 1; ks < 9; ++ks) {
            bf16x8 a[2];   // chunk 2ks+h
            const int cb = (2 * ks + h) * 64;
            a[0] = *(const bf16x8*)(ab + (cb + l31) * 16);
            a[1] = *(const bf16x8*)(ab + (cb + 32 + l31) * 16);
#pragma unroll
            for (int hi2 = 0; hi2 < 2; ++hi2)
#pragma unroll
                for (int bj2 = 0; bj2 < 2; ++bj2)
                    acc[hi2][bj2] = __builtin_amdgcn_mfma_f32_32x32x16_bf16(
                        bfrag[hi2][ks], a[bj2], acc[hi2][bj2], 0, 0, 0);
        }

        // ---- epilogue: relu(acc) * W2 (b1 already in acc).
        float sarr[2];
#pragma unroll
        for (int bj2 = 0; bj2 < 2; ++bj2) {
            float sr0 = 0.f, sr1 = 0.f, sr2 = 0.f, sr3 = 0.f;
#pragma unroll
            for (int hi2 = 0; hi2 < 2; ++hi2)
#pragma unroll
                for (int q = 0; q < 4; ++q) {
                    float h0 = acc[hi2][bj2][q*4+0]; h0 = h0 > 0.f ? h0 : 0.f;
                    float h1 = acc[hi2][bj2][q*4+1]; h1 = h1 > 0.f ? h1 : 0.f;
                    float h2 = acc[hi2][bj2][q*4+2]; h2 = h2 > 0.f ? h2 : 0.f;
                    float h3 = acc[hi2][bj2][q*4+3]; h3 = h3 > 0.f ? h3 : 0.f;
                    sr0 = fmaf(h0, w2v[hi2][q*4+0], sr0);
                    sr1 = fmaf(h1, w2v[hi2][q*4+1], sr1);
                    sr2 = fmaf(h2, w2v[hi2][q*4+2], sr2);
                    sr3 = fmaf(h3, w2v[hi2][q*4+3], sr3);
                }
            float s = (sr0 + sr1) + (sr2 + sr3);
            // lanes l and l+32 hold complementary hid rows of the same batch col
            s += __shfl_xor(s, 32, 64);
            sarr[bj2] = s;
        }
        if (h == 0) {
            partial[cur][w][l31]      = sarr[0];
            partial[cur][w][32 + l31] = sarr[1];
        }

        __syncthreads();   // partial ready; stage(tile+1) drained; Abuf[cur] free
        if (t < 64) {
            float v = (partial[cur][0][t] + partial[cur][1][t])
                    + (partial[cur][2][t] + partial[cur][3][t])
                    + b2v + skipv;
            out[(size_t)(r0 + t) * NF + m] = v;
        }
    }
#undef STAGE
}

// ---------------------------------------------------------------------------
extern "C" void kernel_launch(void* const* d_in, const int* in_sizes, int n_in,
                              void* d_out, int out_size, void* d_ws, size_t ws_size,
                              hipStream_t stream) {
    const float* f_t = (const float*)d_in[0];
    const float* a_t = (const float*)d_in[1];
    const float* W1  = (const float*)d_in[2];
    const float* b1  = (const float*)d_in[3];
    const float* W2  = (const float*)d_in[4];
    const float* b2  = (const float*)d_in[5];
    float* out = (float*)d_out;

    // ws layout: w1t bf16 [128][256][144] (9.44 MB),
    //            fabT bf16 [64 tiles][18][64][8] chunk-major (1.18 MB)
    __hip_bfloat16* w1t  = (__hip_bfloat16*)d_ws;
    __hip_bfloat16* fabT = (__hip_bfloat16*)((char*)d_ws + (size_t)NF * HID * KP * 2);

    // converts merged: 1152 w1t blocks + 288 fabT blocks
    hipLaunchKernelGGL(convert_all, dim3(1440), dim3(256), 0, stream,
                       W1, f_t, a_t, w1t, fabT);
    hipLaunchKernelGGL(fused_mlp, dim3(1024), dim3(256), 0, stream,
                       fabT, w1t, b1, W2, b2, f_t, out);
}